// Round 10
// baseline (244.867 us; speedup 1.0000x reference)
//
#include <hip/hip_runtime.h>
#include <math.h>

#define NX   160
#define N2   25600        // 160*160
#define N3   4096000      // 160^3
#define NB   4

#define Z_SLAB 10
#define NBLK_F 1600       // 25 tiles * 16 slabs * 4 batches
#define NBLK_S 1000       // sums kernel blocks (250 per batch)
#define SBLK_PER_B 250

#define SA_W 52           // 48 cols + 4 pad floats
#define SB_W 36           // 32 cols + 4 pad floats

// 1D Gaussian taps exp(-d^2/50), d=-4..4 (NOT normalized, matches reference)
__device__ __constant__ float G1[9] = {
    0.72614903f, 0.83527021f, 0.92311635f, 0.98019867f, 1.0f,
    0.98019867f, 0.92311635f, 0.83527021f, 0.72614903f};

// edge sums: FULL - missing taps at low/high boundary
#define ES_FULL 7.92946852f
__device__ __constant__ float ES_M[4] = {3.46473426f, 2.48453559f, 1.56141924f,
                                         0.72614903f};
__device__ inline float edge_sum(int i) {
    float s = ES_FULL;
    if (i < 4) s -= ES_M[i];
    if (i > NX - 5) s -= ES_M[NX - 1 - i];
    return s;
}

__device__ inline float4 f4_zero() { return make_float4(0.f, 0.f, 0.f, 0.f); }
__device__ inline float4 f4_axpy(float a, float4 b, float4 c) {
    return make_float4(c.x + a * b.x, c.y + a * b.y, c.z + a * b.z, c.w + a * b.w);
}

// block = 256 threads (4 waves). Reduce NV doubles, plain store.
// NO atomics, NO fences (R4: fences+tickets cost ~600us).
template <int NV>
__device__ inline void block_reduce_store(double* vals, double* dst) {
    __shared__ double red[4][NV];
    int lane = threadIdx.x & 63;
    int wave = threadIdx.x >> 6;
#pragma unroll
    for (int v = 0; v < NV; ++v) {
        double x = vals[v];
#pragma unroll
        for (int off = 32; off > 0; off >>= 1) x += __shfl_down(x, off, 64);
        if (lane == 0) red[wave][v] = x;
    }
    __syncthreads();
    if (threadIdx.x < NV) {
        int v = threadIdx.x;
        dst[v] = red[0][v] + red[1][v] + red[2][v] + red[3][v];
    }
}

// One xy-conv'd t-plane for this block's 32x32 tile, returning this thread's
// float4 (rows y0+oy, cols x0+4*x4). Proven conv_xy pipeline: stage sA ->
// x-conv -> sB -> y-conv. 2 barriers; caller must invoke block-uniformly.
// Barrier safety across consecutive calls: next call's sA stores come after
// this call's 2nd barrier (protects x-conv's sA reads); next call's sB writes
// come after next call's 1st barrier (protects this call's y-conv sB reads).
__device__ inline float4 t_plane(const float* __restrict__ labels,
                                 float* sA, float* sB, int planeOff,
                                 int x0, int y0, int tid, int oy, int x4) {
    // stage 40 rows x 12 float4 of labels (zero-padded outside volume)
    for (int i = tid; i < 480; i += 256) {
        int row = i / 12, c = i % 12;
        int gx = x0 - 8 + 4 * c;
        int gy = y0 - 4 + row;
        float4 v = f4_zero();
        if (gy >= 0 && gy < NX && gx >= 0 && gx <= NX - 4)
            v = *(const float4*)&labels[planeOff + gy * NX + gx];
        *(float4*)&sA[row * SA_W + 4 * c] = v;
    }
    __syncthreads();

    // x-conv: 40 rows x 8 float4 outputs
    for (int i = tid; i < 320; i += 256) {
        int r = i >> 3, xx = i & 7;
        const float* row = &sA[r * SA_W + 4 * xx];
        float4 a = *(const float4*)&row[4];
        float4 b = *(const float4*)&row[8];
        float4 c = *(const float4*)&row[12];
        float w[12] = {a.x, a.y, a.z, a.w, b.x, b.y, b.z, b.w,
                       c.x, c.y, c.z, c.w};
        float4 o = f4_zero();
#pragma unroll
        for (int d = 0; d < 9; ++d) {
            float g = G1[d];
            o.x += g * w[d];
            o.y += g * w[d + 1];
            o.z += g * w[d + 2];
            o.w += g * w[d + 3];
        }
        *(float4*)&sB[r * SB_W + 4 * xx] = o;
    }
    __syncthreads();

    // y-conv for own output row
    float4 acc = f4_zero();
#pragma unroll
    for (int d = 0; d < 9; ++d) {
        float4 v = *(const float4*)&sB[(oy + d) * SB_W + 4 * x4];
        acc = f4_axpy(G1[d], v, acc);
    }
    return acc;
}

// Streaming reduction: per-batch (sum p, sum in*p, sum in) partials.
// 250 blocks per batch; each thread 16 float4 pairs, fully coalesced.
__global__ __launch_bounds__(256) void sums_kernel(
    const float* __restrict__ labels, const float* __restrict__ inputs,
    double* __restrict__ pS) {
    int bid = blockIdx.x, tid = threadIdx.x;
    int b = bid / SBLK_PER_B;
    int blk = bid % SBLK_PER_B;
    int base = b * N3;
    float sp = 0.f, sip = 0.f, si = 0.f;
#pragma unroll 4
    for (int k = 0; k < 16; ++k) {
        int f4i = blk * 256 + tid + k * 64000;  // < 1,024,000
        int gi = base + 4 * f4i;
        float4 p = *(const float4*)&labels[gi];
        float4 in = *(const float4*)&inputs[gi];
        sp += p.x + p.y + p.z + p.w;
        sip += in.x * p.x + in.y * p.y + in.z * p.z + in.w * p.w;
        si += in.x + in.y + in.z + in.w;
    }
    double vals[3] = {(double)sp, (double)sip, (double)si};
    block_reduce_store<3>(vals, pS + 3 * bid);
}

// one block per batch: sum 250 partials -> S[3b+v]
__global__ __launch_bounds__(256) void reduce_S_kernel(
    const double* __restrict__ pS, double* __restrict__ S) {
    int b = blockIdx.x;
    double v0 = 0, v1 = 0, v2 = 0;
    for (int i = threadIdx.x; i < SBLK_PER_B; i += 256) {
        const double* p = pS + 3 * (b * SBLK_PER_B + i);
        v0 += p[0]; v1 += p[1]; v2 += p[2];
    }
    double vals[3] = {v0, v1, v2};
    block_reduce_store<3>(vals, S + 3 * b);
}

// Fused xy+z conv + loss accumulation: no t buffer, no t traffic.
// Block = 32x32 xy-tile, z-slab of 10 outputs; 9-deep register window of
// on-the-fly t-planes (1.8x redundant xy-conv on halo planes; labels halo
// reads are L3-absorbed). Per-block partials {n0,d0,n1,d1} -> pZ.
__global__ __launch_bounds__(256) void fused_xyz_kernel(
    const float* __restrict__ labels, const float* __restrict__ inputs,
    const double* __restrict__ S, double* __restrict__ pZ) {
    __shared__ float sA[40 * SA_W];
    __shared__ float sB[40 * SB_W];

    int tid = threadIdx.x;
    int bid = blockIdx.x;
    int tileX = bid % 5;
    int tileY = (bid / 5) % 5;
    int slab = (bid / 25) % 16;
    int b = bid / 400;
    int x0 = tileX * 32, y0 = tileY * 32, z0 = slab * Z_SLAB;
    int oy = tid >> 3, x4 = tid & 7;
    int volBase = b * N3;

    // per-batch means (class 0: p, class 1: 1-p)
    double sp = S[3 * b + 0], sip = S[3 * b + 1], si = S[3 * b + 2];
    const double Nv = (double)N3;
    float m0 = (float)((sip / Nv) / (sp / Nv + 1e-5));
    float m1 = (float)(((si - sip) / Nv) / ((Nv - sp) / Nv + 1e-5));

    int gx = x0 + 4 * x4;
    float ey = edge_sum(y0 + oy);
    float cx[4] = {edge_sum(gx) * ey, edge_sum(gx + 1) * ey,
                   edge_sum(gx + 2) * ey, edge_sum(gx + 3) * ey};
    int ctr = volBase + (y0 + oy) * NX + gx;  // + z*N2 per plane

    // prologue: window of t-planes z0-4 .. z0+4
    float4 win[9];
#pragma unroll
    for (int d = 0; d < 9; ++d) {
        int z = z0 - 4 + d;   // block-uniform
        win[d] = (z >= 0 && z < NX)
                     ? t_plane(labels, sA, sB, volBase + z * N2, x0, y0, tid, oy, x4)
                     : f4_zero();
    }

    float n0 = 0.f, d0 = 0.f, n1 = 0.f, d1 = 0.f;
    for (int j = 0; j < Z_SLAB; ++j) {
        int z = z0 + j;
        float4 c4 = f4_zero();
#pragma unroll
        for (int d = 0; d < 9; ++d) c4 = f4_axpy(G1[d], win[d], c4);

        float4 pv = *(const float4*)&labels[ctr + z * N2];
        float4 iv = *(const float4*)&inputs[ctr + z * N2];
        float ez = edge_sum(z);
        float pc[4] = {pv.x, pv.y, pv.z, pv.w};
        float ic[4] = {iv.x, iv.y, iv.z, iv.w};
        float cc[4] = {c4.x, c4.y, c4.z, c4.w};
#pragma unroll
        for (int l = 0; l < 4; ++l) {
            float c1 = cx[l] * ez - cc[l];  // conv(1-p) via conv(ones)
            float df0 = ic[l] - m0; df0 *= df0;
            float w0 = __expf(-df0 * df0);
            float df1 = ic[l] - m1; df1 *= df1;
            float w1 = __expf(-df1 * df1);
            n0 += cc[l] * pc[l] * w0;
            d0 += cc[l] * w0;
            n1 += c1 * (1.f - pc[l]) * w1;
            d1 += c1 * w1;
        }

        // advance window (skip after last output); block-uniform branches
        if (j < Z_SLAB - 1) {
            int zn = z0 + j + 5;
            float4 nw = (zn < NX)
                            ? t_plane(labels, sA, sB, volBase + zn * N2, x0, y0, tid, oy, x4)
                            : f4_zero();
#pragma unroll
            for (int d = 0; d < 8; ++d) win[d] = win[d + 1];
            win[8] = nw;
        }
    }
    double vals[4] = {(double)n0, (double)d0, (double)n1, (double)d1};
    block_reduce_store<4>(vals, pZ + 4 * bid);
}

// single block: sum 1600 per-block partials, compute final loss
__global__ __launch_bounds__(256) void finalize_kernel(
    const double* __restrict__ pZ, float* __restrict__ out) {
    double a0 = 0, a1 = 0, a2 = 0, a3 = 0;
    for (int i = threadIdx.x; i < NBLK_F; i += 256) {
        const double* p = &pZ[4 * i];
        a0 += p[0]; a1 += p[1]; a2 += p[2]; a3 += p[3];
    }
    __shared__ double red[4][4];
    int lane = threadIdx.x & 63;
    int wave = threadIdx.x >> 6;
    double vals[4] = {a0, a1, a2, a3};
#pragma unroll
    for (int v = 0; v < 4; ++v) {
        double x = vals[v];
#pragma unroll
        for (int off = 32; off > 0; off >>= 1) x += __shfl_down(x, off, 64);
        if (lane == 0) red[wave][v] = x;
    }
    __syncthreads();
    if (threadIdx.x == 0) {
        double acc[4];
#pragma unroll
        for (int v = 0; v < 4; ++v)
            acc[v] = red[0][v] + red[1][v] + red[2][v] + red[3][v];
        double r0 = fabs(acc[0] / (acc[1] + 1e-6));
        double r1 = fabs(acc[2] / (acc[3] + 1e-6));
        out[0] = (float)(2.0 - r0 - r1);
    }
}

extern "C" void kernel_launch(void* const* d_in, const int* in_sizes, int n_in,
                              void* d_out, int out_size, void* d_ws, size_t ws_size,
                              hipStream_t stream) {
    const float* labels = (const float*)d_in[0];
    const float* inputs = (const float*)d_in[1];
    float* out = (float*)d_out;

    // ws layout — total < 80 KB (no t buffer):
    //   [0)      pS : 1000*3 doubles = 24000 B
    //   [24064)  S  : 12 doubles
    //   [24320)  pZ : 1600*4 doubles = 51200 B
    double* pS = (double*)d_ws;
    double* S  = (double*)((char*)d_ws + 24064);
    double* pZ = (double*)((char*)d_ws + 24320);

    hipLaunchKernelGGL(sums_kernel, dim3(NBLK_S), dim3(256), 0, stream,
                       labels, inputs, pS);
    hipLaunchKernelGGL(reduce_S_kernel, dim3(NB), dim3(256), 0, stream, pS, S);
    hipLaunchKernelGGL(fused_xyz_kernel, dim3(NBLK_F), dim3(256), 0, stream,
                       labels, inputs, S, pZ);
    hipLaunchKernelGGL(finalize_kernel, dim3(1), dim3(256), 0, stream, pZ, out);
}